// Round 13
// baseline (214.292 us; speedup 1.0000x reference)
//
#include <hip/hip_runtime.h>

#define DEV __device__ __forceinline__

typedef float f32x4 __attribute__((ext_vector_type(4)));
typedef short s16x8 __attribute__((ext_vector_type(8)));
typedef unsigned short u16;
typedef unsigned int u32;

constexpr int Bb = 2, Tt = 2048, DIMc = 1024, Hh = 8, Ee = 5, Dd = 64;
constexpr int NTOK = Bb * Tt;   // 4096
constexpr int NQ = Hh * Ee * Dd; // 2560

DEV u16 f2bf(float f) {
  union { float f; u32 u; } v; v.f = f;
  u32 r = v.u + 0x7fffu + ((v.u >> 16) & 1u);
  return (u16)(r >> 16);
}

DEV u32 pk2(float a, float b) {  // two f32 -> packed bf16 pair (a=lo, b=hi)
  return (u32)f2bf(a) | ((u32)f2bf(b) << 16);
}

DEV s16x8 ld8(const u16* p) {
  uint4 u = *reinterpret_cast<const uint4*>(p);
  return __builtin_bit_cast(s16x8, u);
}

DEV f32x4 mfma16(s16x8 a, s16x8 b, f32x4 c) {
  return __builtin_amdgcn_mfma_f32_16x16x32_bf16(a, b, c, 0, 0, 0);
}

// async global->LDS, 16B per lane. LDS dest = uniform base + lane*16.
DEV void gld16(const void* g, void* l) {
  __builtin_amdgcn_global_load_lds(
      (const __attribute__((address_space(1))) void*)g,
      (__attribute__((address_space(3))) void*)l, 16, 0, 0);
}

// ---------- fused prep kernel ----------
// blocks [0,4096): cvt x->bf16 ; [4096,11776): transpose w_q/w_kv -> wT ;
// [11776,12032): w_o_w -> woT ; [12032,12036): bias sum ; [12036,12116): wsdT.
__launch_bounds__(256)
__global__ void k_prep(const float* __restrict__ x, const float* __restrict__ wq,
                       const float* __restrict__ wkv, const float* __restrict__ wow,
                       const float* __restrict__ wob, const float* __restrict__ wsr,
                       const float* __restrict__ wdr,
                       u16* __restrict__ xb, u16* __restrict__ wT,
                       u16* __restrict__ woT, float* __restrict__ bsum,
                       float* __restrict__ wsdT) {
  int bid = blockIdx.x, t = threadIdx.x;
  if (bid < 4096) {
    int i = bid * 256 + t;
    float4 v = reinterpret_cast<const float4*>(x)[i];
    u16 r0 = f2bf(v.x), r1 = f2bf(v.y), r2 = f2bf(v.z), r3 = f2bf(v.w);
    u32 lo = (u32)r0 | ((u32)r1 << 16);
    u32 hi = (u32)r2 | ((u32)r3 << 16);
    reinterpret_cast<uint2*>(xb)[i] = make_uint2(lo, hi);
  } else if (bid < 11776) {
    int b2 = bid - 4096;
    int R0 = (b2 % 240) * 32;
    int C0 = (b2 / 240) * 32;
    int s = R0 / 2560, rem = R0 % 2560;
    int h = rem / 320, n0 = rem % 320;
    const float* src; int ld; int col0;
    if (s == 0) { src = wq;  ld = 2560; col0 = h * 320 + n0; }
    else        { src = wkv; ld = 5120; col0 = (s - 1) * 2560 + h * 320 + n0; }
    __shared__ float tile[32][33];
    int tx = t & 31, ty = t >> 5;
    #pragma unroll
    for (int i = 0; i < 4; i++) {
      int c = C0 + ty + 8 * i;
      tile[ty + 8 * i][tx] = src[(size_t)c * ld + col0 + tx];
    }
    __syncthreads();
    #pragma unroll
    for (int i = 0; i < 4; i++) {
      int n = ty + 8 * i;
      wT[(size_t)(R0 + n) * 1024 + C0 + tx] = f2bf(tile[tx][n]);
    }
  } else if (bid < 12032) {
    int b2 = bid - 11776;
    int f = b2 * 4 + (t >> 6), d = t & 63;
    #pragma unroll
    for (int h = 0; h < 8; h++)
      woT[(size_t)f * 512 + h * 64 + d] = f2bf(wow[((size_t)h * 1024 + f) * 64 + d]);
  } else if (bid < 12036) {
    int f = (bid - 12032) * 256 + t;
    float s = 0.f;
    #pragma unroll
    for (int h = 0; h < 8; h++) s += wob[h * 1024 + f];
    bsum[f] = s;
  } else {
    int j = bid - 12036;
    const float* src = (j < 40) ? wsr : wdr;
    int c = (j < 40) ? j : j - 40;
    for (int i = t; i < 1024; i += 256)
      wsdT[(size_t)j * 1024 + i] = src[(size_t)i * 40 + c];
  }
}

// ---------- scores + topk (all fp32) ----------
__launch_bounds__(320)
__global__ void k_scores(const float* __restrict__ x, const float* __restrict__ wsdT,
                         int* __restrict__ eps_s, int* __restrict__ eps_d,
                         float* __restrict__ ss3, float* __restrict__ sd3) {
  int tokb = blockIdx.x * 8;
  __shared__ float xl[8][1028];
  __shared__ float sc[8][80];
  const float4* xsrc = reinterpret_cast<const float4*>(x + (size_t)tokb * 1024);
  for (int i = threadIdx.x; i < 2048; i += 320) {
    int tok = i >> 8, col4 = i & 255;
    *reinterpret_cast<float4*>(&xl[tok][col4 * 4]) = xsrc[i];
  }
  __syncthreads();
  {
    int tok = threadIdx.x & 7, j = threadIdx.x >> 3;
    const float4* wsp = reinterpret_cast<const float4*>(wsdT + (size_t)j * 1024);
    const float4* wdp = reinterpret_cast<const float4*>(wsdT + (size_t)(j + 40) * 1024);
    float as0 = 0.f, as1 = 0.f, ad0 = 0.f, ad1 = 0.f;
    #pragma unroll 4
    for (int k4 = 0; k4 < 256; k4 += 2) {
      float4 x0 = *reinterpret_cast<const float4*>(&xl[tok][k4 * 4]);
      float4 x1 = *reinterpret_cast<const float4*>(&xl[tok][k4 * 4 + 4]);
      float4 wsv0 = wsp[k4], wsv1 = wsp[k4 + 1];
      float4 wdv0 = wdp[k4], wdv1 = wdp[k4 + 1];
      as0 += x0.x * wsv0.x + x0.y * wsv0.y + x0.z * wsv0.z + x0.w * wsv0.w;
      as1 += x1.x * wsv1.x + x1.y * wsv1.y + x1.z * wsv1.z + x1.w * wsv1.w;
      ad0 += x0.x * wdv0.x + x0.y * wdv0.y + x0.z * wdv0.z + x0.w * wdv0.w;
      ad1 += x1.x * wdv1.x + x1.y * wdv1.y + x1.z * wdv1.z + x1.w * wdv1.w;
    }
    float as = as0 + as1, ad = ad0 + ad1;
    sc[tok][j]      = 1.f / (1.f + expf(-as));
    sc[tok][40 + j] = 1.f / (1.f + expf(-ad));
  }
  __syncthreads();
  int t2 = threadIdx.x;
  if (t2 < 128) {
    int tt = t2 >> 4, u = t2 & 15, h = u >> 1, which = u & 1;
    const float* S = &sc[tt][which * 40 + h * 5];
    float v[5];
    #pragma unroll
    for (int e = 0; e < 5; e++) v[e] = S[e];
    int tok = tokb + tt;
    int base = (tok * 8 + h) * 3;
    int* eps = which ? eps_d : eps_s;
    float* w3 = which ? sd3 : ss3;
    bool used[5] = {false, false, false, false, false};
    #pragma unroll
    for (int kk = 0; kk < 3; kk++) {
      float best = -1e30f; int bi = 0;
      #pragma unroll
      for (int e = 0; e < 5; e++)
        if (!used[e] && v[e] > best) { best = v[e]; bi = e; }
      used[bi] = true;
      eps[base + kk] = bi;
    }
    #pragma unroll
    for (int kk = 0; kk < 3; kk++) w3[base + kk] = S[kk]; // FIRST-K raw scores
  }
}

// ---------- fused projection + expert-select (counted-vmcnt pipeline) ----------
// grid (32, 8, 3)  block 512 (8 waves). M=128, N=320, K=1024, BK=64.
// Double-buffered LDS (112KB, 1 block/CU). Per K-tile: issue next tile's 7
// gld16, s_waitcnt vmcnt(7) (previous tile's loads done, next's in flight),
// raw s_barrier, compute 40 MFMA, raw s_barrier. Never vmcnt(0) in the loop.
__launch_bounds__(512)
__global__ void k_proj(const u16* __restrict__ xb, const u16* __restrict__ wT,
                       const int* __restrict__ eps_d, const int* __restrict__ eps_s,
                       const float* __restrict__ sd3, const float* __restrict__ ss3,
                       u16* __restrict__ qw, u16* __restrict__ kw, u16* __restrict__ vw) {
  int tok0 = blockIdx.x * 128;
  int h = blockIdx.y;
  int s = blockIdx.z;
  int Rbase = (s * 8 + h) * 320;
  __shared__ alignas(16) u16 bsA[2][128 * 64];   // 32 KB
  __shared__ alignas(16) u16 bsB[2][320 * 64];   // 80 KB
  int wv = threadIdx.x >> 6, l = threadIdx.x & 63;
  int g = l >> 4, c = l & 15;
  f32x4 acc[20];
  #pragma unroll
  for (int i = 0; i < 20; i++) acc[i] = (f32x4){0.f, 0.f, 0.f, 0.f};

  const u16* wTp0 = wT + (size_t)Rbase * 1024;
  const u16* xbp0 = xb + (size_t)tok0 * 1024;

#define STAGE(BUF, K0)                                                        \
  {                                                                           \
    const u16* wTp = wTp0 + (K0);                                             \
    _Pragma("unroll")                                                         \
    for (int j = 0; j < 5; j++) {                                             \
      int ch = wv * 320 + j * 64 + l;                                         \
      int row = ch >> 3, part = ch & 7;                                       \
      gld16(wTp + (size_t)row * 1024 + ((part * 8) ^ ((row & 7) * 8)),        \
            &bsB[BUF][(wv * 320 + j * 64) * 8]);                              \
    }                                                                         \
    const u16* xbp = xbp0 + (K0);                                             \
    _Pragma("unroll")                                                         \
    for (int j = 0; j < 2; j++) {                                             \
      int ch = wv * 128 + j * 64 + l;                                         \
      int row = ch >> 3, part = ch & 7;                                       \
      gld16(xbp + (size_t)row * 1024 + ((part * 8) ^ ((row & 7) * 8)),        \
            &bsA[BUF][(wv * 128 + j * 64) * 8]);                              \
    }                                                                         \
  }

#define COMPUTE(BUF)                                                          \
  {                                                                           \
    _Pragma("unroll")                                                         \
    for (int kk = 0; kk < 2; kk++) {                                          \
      int off = (kk * 32 + g * 8) ^ ((c & 7) * 8);                            \
      s16x8 a = *reinterpret_cast<const s16x8*>(&bsA[BUF][(wv * 16 + c) * 64 + off]); \
      _Pragma("unroll")                                                       \
      for (int nt = 0; nt < 20; nt++) {                                       \
        s16x8 b = *reinterpret_cast<const s16x8*>(&bsB[BUF][(nt * 16 + c) * 64 + off]); \
        acc[nt] = mfma16(a, b, acc[nt]);                                      \
      }                                                                       \
    }                                                                         \
  }

  STAGE(0, 0)
  for (int t = 0; t < 15; ++t) {
    STAGE((t + 1) & 1, (t + 1) * 64)
    asm volatile("s_waitcnt vmcnt(7)" ::: "memory");
    __builtin_amdgcn_s_barrier();
    __builtin_amdgcn_sched_barrier(0);
    COMPUTE(t & 1)
    __builtin_amdgcn_sched_barrier(0);
    __builtin_amdgcn_s_barrier();
  }
  asm volatile("s_waitcnt vmcnt(0)" ::: "memory");
  __builtin_amdgcn_s_barrier();
  __builtin_amdgcn_sched_barrier(0);
  COMPUTE(1)
#undef STAGE
#undef COMPUTE

  const int* eps = (s == 0) ? eps_d : eps_s;
  const float* w3 = (s == 0) ? sd3 : ss3;
  float scale = (s == 0) ? 0.125f : 1.0f;
  u16* dst = (s == 0) ? qw : (s == 1 ? kw : vw);
  #pragma unroll
  for (int r = 0; r < 4; r++) {
    int tokr = tok0 + wv * 16 + g * 4 + r;
    int base = (tokr * 8 + h) * 3;
    int e0 = eps[base], e1 = eps[base + 1], e2 = eps[base + 2];
    float w0 = w3[base], w1 = w3[base + 1], w2 = w3[base + 2];
    float we[5];
    #pragma unroll
    for (int e = 0; e < 5; e++)
      we[e] = (e0 == e ? w0 : 0.f) + (e1 == e ? w1 : 0.f) + (e2 == e ? w2 : 0.f);
    int b = tokr >> 11, t = tokr & 2047;
    size_t obase = (((size_t)b * 8 + h) * 2048 + t) * 64;
    #pragma unroll
    for (int dh = 0; dh < 4; dh++) {
      float vq = 0.f;
      #pragma unroll
      for (int e = 0; e < 5; e++) vq += we[e] * acc[e * 4 + dh][r];
      dst[obase + dh * 16 + c] = f2bf(vq * scale);
    }
  }
}

// (B,H,T,D) -> (B,H,D,T') with T' mu-permuted inside each 32-key tile:
// storage position p(k) = 8*((k&15)>>2) + (k&3) + (k>=16 ? 4 : 0).
__global__ void k_trv(const u16* __restrict__ vw, u16* __restrict__ vT) {
  int bh = blockIdx.z;
  int t0 = blockIdx.x * 32, d0 = blockIdx.y * 32;
  __shared__ u16 tile[32][33];
  const u16* src = vw + (size_t)bh * 2048 * 64;
  u16* dst = vT + (size_t)bh * 64 * 2048;
  int tx = threadIdx.x, ty = threadIdx.y;
  #pragma unroll
  for (int i = 0; i < 4; i++)
    tile[ty + 8 * i][tx] = src[(size_t)(t0 + ty + 8 * i) * 64 + d0 + tx];
  __syncthreads();
  int p = 8 * ((tx & 15) >> 2) + (tx & 3) + ((tx >= 16) ? 4 : 0);
  #pragma unroll
  for (int i = 0; i < 4; i++)
    dst[(size_t)(d0 + ty + 8 * i) * 2048 + t0 + p] = tile[tx][ty + 8 * i];
}

// ---------- flash attention: 8 waves, split-KV x2, LDS-staged K/V ----------
__launch_bounds__(512)
__global__ void k_attn(const u16* __restrict__ qw, const u16* __restrict__ kw,
                       const u16* __restrict__ vT, u16* __restrict__ ow) {
  int bh = blockIdx.y;
  int b = bh >> 3, h = bh & 7;
  int q0 = blockIdx.x * 64;
  int wv = threadIdx.x >> 6, l = threadIdx.x & 63;
  int seg = wv >> 2, wq = wv & 3;
  int g = l >> 4, c = l & 15;
  const u16* qp = qw + (size_t)bh * 2048 * 64;
  const u16* kp = kw + (size_t)bh * 2048 * 64;
  const u16* vp = vT + (size_t)bh * 64 * 2048;
  __shared__ alignas(16) u16 Kl[2][128 * 64];   // 32 KB
  __shared__ alignas(16) u16 Vl[2][64 * 128];   // 32 KB

  s16x8 qa0 = ld8(qp + (size_t)(q0 + wq * 16 + c) * 64 + 0 + 8 * g);
  s16x8 qa1 = ld8(qp + (size_t)(q0 + wq * 16 + c) * 64 + 32 + 8 * g);

  f32x4 o[4];
  #pragma unroll
  for (int i = 0; i < 4; i++) o[i] = (f32x4){0.f, 0.f, 0.f, 0.f};
  float ssum = 0.f;

  const int kb0 = seg * 1024;
  for (int kt = 0; kt < 1024; kt += 128) {
    int kbase = kb0 + kt;
    __syncthreads();
    #pragma unroll
    for (int j = 0; j < 4; j++) {
      int ch = (wq * 4 + j) * 64 + l;
      int row = ch >> 3, sl = ch & 7;
      gld16(kp + (size_t)(kbase + row) * 64 + ((sl ^ (row & 7)) * 8),
            &Kl[seg][(wq * 4 + j) * 64 * 8]);
    }
    #pragma unroll
    for (int j = 0; j < 4; j++) {
      int ch = (wq * 4 + j) * 64 + l;
      int d = ch >> 4, sl = ch & 15;
      gld16(vp + (size_t)d * 2048 + kbase + ((sl ^ (d & 15)) * 8),
            &Vl[seg][(wq * 4 + j) * 64 * 8]);
    }
    __syncthreads();

    #pragma unroll
    for (int kk = 0; kk < 4; kk++) {
      int r0 = kk * 32 + c, r1 = kk * 32 + 16 + c;
      int c7 = c & 7;
      s16x8 ka0 = *reinterpret_cast<const s16x8*>(&Kl[seg][r0 * 64 + ((0 + g) ^ c7) * 8]);
      s16x8 ka1 = *reinterpret_cast<const s16x8*>(&Kl[seg][r0 * 64 + ((4 + g) ^ c7) * 8]);
      s16x8 kc0 = *reinterpret_cast<const s16x8*>(&Kl[seg][r1 * 64 + ((0 + g) ^ c7) * 8]);
      s16x8 kc1 = *reinterpret_cast<const s16x8*>(&Kl[seg][r1 * 64 + ((4 + g) ^ c7) * 8]);

      f32x4 s0 = (f32x4){0.f, 0.f, 0.f, 0.f};
      f32x4 s1 = (f32x4){0.f, 0.f, 0.f, 0.f};
      s0 = mfma16(ka0, qa0, s0);
      s0 = mfma16(ka1, qa1, s0);
      s1 = mfma16(kc0, qa0, s1);
      s1 = mfma16(kc1, qa1, s1);

      float p00 = __expf(s0[0]), p01 = __expf(s0[1]);
      float p02 = __expf(s0[2]), p03 = __expf(s0[3]);
      float p10 = __expf(s1[0]), p11 = __expf(s1[1]);
      float p12 = __expf(s1[2]), p13 = __expf(s1[3]);
      ssum += (p00 + p01) + (p02 + p03) + (p10 + p11) + (p12 + p13);

      uint4 pw = make_uint4(pk2(p00, p01), pk2(p02, p03),
                            pk2(p10, p11), pk2(p12, p13));
      s16x8 pa = __builtin_bit_cast(s16x8, pw);

      #pragma unroll
      for (int nt = 0; nt < 4; nt++) {
        int d = nt * 16 + c;
        s16x8 vb = *reinterpret_cast<const s16x8*>(&Vl[seg][d * 128 + (((kk * 4 + g) ^ (d & 15)) * 8)]);
        o[nt] = mfma16(pa, vb, o[nt]);
      }
    }
  }

  // per-lane ssum covers this seg's keys for q=c; reduce over g (bits 4,5).
  ssum += __shfl_xor(ssum, 16, 64);
  ssum += __shfl_xor(ssum, 32, 64);

  // combine epilogue: alias os/ssl onto Kl/Vl after all LDS reads complete.
  float* osp  = reinterpret_cast<float*>(&Kl[0][0]);   // [4][16][64] = 16 KB
  float* sslp = reinterpret_cast<float*>(&Vl[0][0]);   // [2][4][16]
  __syncthreads();
  if (g == 0) sslp[seg * 64 + wq * 16 + c] = ssum;
  if (seg == 1) {
    #pragma unroll
    for (int r = 0; r < 4; r++)
      #pragma unroll
      for (int nt = 0; nt < 4; nt++)
        osp[(wq * 16 + g * 4 + r) * 64 + nt * 16 + c] = o[nt][r];
  }
  __syncthreads();
  if (seg == 0) {
    #pragma unroll
    for (int r = 0; r < 4; r++) {
      int q = g * 4 + r;
      float sm = sslp[wq * 16 + q] + sslp[64 + wq * 16 + q];
      float inv = 1.f / sm;
      int t = q0 + wq * 16 + q;
      #pragma unroll
      for (int nt = 0; nt < 4; nt++) {
        float val = (o[nt][r] + osp[(wq * 16 + q) * 64 + nt * 16 + c]) * inv;
        ow[((size_t)(b * 2048 + t)) * 512 + h * 64 + nt * 16 + c] = f2bf(val);
      }
    }
  }
}

// ---------- output projection ----------
__launch_bounds__(512)
__global__ void k_oproj(const u16* __restrict__ ow, const u16* __restrict__ woT,
                        const float* __restrict__ biasum, float* __restrict__ out) {
  int t0 = blockIdx.x * 128, f0 = blockIdx.y * 64;
  int wv = threadIdx.x >> 6, l = threadIdx.x & 63;
  int g = l >> 4, c = l & 15;
  f32x4 acc[4];
  #pragma unroll
  for (int i = 0; i < 4; i++) acc[i] = (f32x4){0.f, 0.f, 0.f, 0.f};
  for (int k0 = 0; k0 < 512; k0 += 32) {
    s16x8 a = ld8(ow + (size_t)(t0 + wv * 16 + c) * 512 + k0 + 8 * g);
    #pragma unroll
    for (int nt = 0; nt < 4; nt++) {
      s16x8 bfr = ld8(woT + (size_t)(f0 + nt * 16 + c) * 512 + k0 + 8 * g);
      acc[nt] = mfma16(a, bfr, acc[nt]);
    }
  }
  #pragma unroll
  for (int r = 0; r < 4; r++) {
    int t = t0 + wv * 16 + g * 4 + r;
    #pragma unroll
    for (int nt = 0; nt < 4; nt++) {
      int f = f0 + nt * 16 + c;
      out[(size_t)t * 1024 + f] = acc[nt][r] + biasum[f];
    }
  }
}

extern "C" void kernel_launch(void* const* d_in, const int* in_sizes, int n_in,
                              void* d_out, int out_size, void* d_ws, size_t ws_size,
                              hipStream_t stream) {
  const float* x    = (const float*)d_in[0];
  const float* w_q  = (const float*)d_in[1];
  const float* w_kv = (const float*)d_in[2];
  const float* w_s  = (const float*)d_in[3];
  const float* w_d  = (const float*)d_in[4];
  const float* w_ow = (const float*)d_in[5];
  const float* w_ob = (const float*)d_in[6];
  float* out = (float*)d_out;

  char* ws = (char*)d_ws;
  size_t o = 0;
  u16* xb     = (u16*)(ws + o); o += (size_t)NTOK * DIMc * 2;
  u16* wT     = (u16*)(ws + o); o += (size_t)3 * NQ * DIMc * 2;
  u16* woT    = (u16*)(ws + o); o += (size_t)1024 * 512 * 2;
  float* bsum = (float*)(ws + o); o += 4096;
  float* wsdT = (float*)(ws + o); o += (size_t)80 * 1024 * 4;
  int* eps_s  = (int*)(ws + o); o += (size_t)NTOK * 8 * 3 * 4;
  int* eps_d  = (int*)(ws + o); o += (size_t)NTOK * 8 * 3 * 4;
  float* ss3  = (float*)(ws + o); o += (size_t)NTOK * 8 * 3 * 4;
  float* sd3  = (float*)(ws + o); o += (size_t)NTOK * 8 * 3 * 4;
  u16* qw     = (u16*)(ws + o); o += (size_t)NTOK * 512 * 2;
  u16* kw     = (u16*)(ws + o); o += (size_t)NTOK * 512 * 2;
  u16* vw     = (u16*)(ws + o); o += (size_t)NTOK * 512 * 2;
  u16* vTw    = (u16*)(ws + o); o += (size_t)NTOK * 512 * 2;
  u16* oww    = (u16*)(ws + o); o += (size_t)NTOK * 512 * 2;

  k_prep<<<12116, 256, 0, stream>>>(x, w_q, w_kv, w_ow, w_ob, w_s, w_d,
                                    xb, wT, woT, bsum, wsdT);
  k_scores<<<512, 320, 0, stream>>>(x, wsdT, eps_s, eps_d, ss3, sd3);
  k_proj<<<dim3(32, 8, 3), 512, 0, stream>>>(xb, wT, eps_d, eps_s, sd3, ss3, qw, kw, vw);
  k_trv<<<dim3(64, 2, 16), dim3(32, 8), 0, stream>>>(vw, vTw);
  k_attn<<<dim3(32, 16), 512, 0, stream>>>(qw, kw, vTw, oww);
  k_oproj<<<dim3(32, 16), 512, 0, stream>>>(oww, woT, bsum, out);
}

// Round 14
// 210.745 us; speedup vs baseline: 1.0168x; 1.0168x over previous
//
#include <hip/hip_runtime.h>

#define DEV __device__ __forceinline__

typedef float f32x4 __attribute__((ext_vector_type(4)));
typedef short s16x8 __attribute__((ext_vector_type(8)));
typedef unsigned short u16;
typedef unsigned int u32;

constexpr int Bb = 2, Tt = 2048, DIMc = 1024, Hh = 8, Ee = 5, Dd = 64;
constexpr int NTOK = Bb * Tt;   // 4096
constexpr int NQ = Hh * Ee * Dd; // 2560

DEV u16 f2bf(float f) {
  union { float f; u32 u; } v; v.f = f;
  u32 r = v.u + 0x7fffu + ((v.u >> 16) & 1u);
  return (u16)(r >> 16);
}

DEV u32 pk2(float a, float b) {  // two f32 -> packed bf16 pair (a=lo, b=hi)
  return (u32)f2bf(a) | ((u32)f2bf(b) << 16);
}

DEV s16x8 ld8(const u16* p) {
  uint4 u = *reinterpret_cast<const uint4*>(p);
  return __builtin_bit_cast(s16x8, u);
}

DEV f32x4 mfma16(s16x8 a, s16x8 b, f32x4 c) {
  return __builtin_amdgcn_mfma_f32_16x16x32_bf16(a, b, c, 0, 0, 0);
}

// async global->LDS, 16B per lane. LDS dest = uniform base + lane*16.
DEV void gld16(const void* g, void* l) {
  __builtin_amdgcn_global_load_lds(
      (const __attribute__((address_space(1))) void*)g,
      (__attribute__((address_space(3))) void*)l, 16, 0, 0);
}

// ---------- fused prep kernel ----------
// blocks [0,4096): cvt x->bf16 ; [4096,11776): transpose w_q/w_kv -> wT ;
// [11776,12032): w_o_w -> woT ; [12032,12036): bias sum ; [12036,12116): wsdT.
__launch_bounds__(256)
__global__ void k_prep(const float* __restrict__ x, const float* __restrict__ wq,
                       const float* __restrict__ wkv, const float* __restrict__ wow,
                       const float* __restrict__ wob, const float* __restrict__ wsr,
                       const float* __restrict__ wdr,
                       u16* __restrict__ xb, u16* __restrict__ wT,
                       u16* __restrict__ woT, float* __restrict__ bsum,
                       float* __restrict__ wsdT) {
  int bid = blockIdx.x, t = threadIdx.x;
  if (bid < 4096) {
    int i = bid * 256 + t;
    float4 v = reinterpret_cast<const float4*>(x)[i];
    u16 r0 = f2bf(v.x), r1 = f2bf(v.y), r2 = f2bf(v.z), r3 = f2bf(v.w);
    u32 lo = (u32)r0 | ((u32)r1 << 16);
    u32 hi = (u32)r2 | ((u32)r3 << 16);
    reinterpret_cast<uint2*>(xb)[i] = make_uint2(lo, hi);
  } else if (bid < 11776) {
    int b2 = bid - 4096;
    int R0 = (b2 % 240) * 32;
    int C0 = (b2 / 240) * 32;
    int s = R0 / 2560, rem = R0 % 2560;
    int h = rem / 320, n0 = rem % 320;
    const float* src; int ld; int col0;
    if (s == 0) { src = wq;  ld = 2560; col0 = h * 320 + n0; }
    else        { src = wkv; ld = 5120; col0 = (s - 1) * 2560 + h * 320 + n0; }
    __shared__ float tile[32][33];
    int tx = t & 31, ty = t >> 5;
    #pragma unroll
    for (int i = 0; i < 4; i++) {
      int c = C0 + ty + 8 * i;
      tile[ty + 8 * i][tx] = src[(size_t)c * ld + col0 + tx];
    }
    __syncthreads();
    #pragma unroll
    for (int i = 0; i < 4; i++) {
      int n = ty + 8 * i;
      wT[(size_t)(R0 + n) * 1024 + C0 + tx] = f2bf(tile[tx][n]);
    }
  } else if (bid < 12032) {
    int b2 = bid - 11776;
    int f = b2 * 4 + (t >> 6), d = t & 63;
    #pragma unroll
    for (int h = 0; h < 8; h++)
      woT[(size_t)f * 512 + h * 64 + d] = f2bf(wow[((size_t)h * 1024 + f) * 64 + d]);
  } else if (bid < 12036) {
    int f = (bid - 12032) * 256 + t;
    float s = 0.f;
    #pragma unroll
    for (int h = 0; h < 8; h++) s += wob[h * 1024 + f];
    bsum[f] = s;
  } else {
    int j = bid - 12036;
    const float* src = (j < 40) ? wsr : wdr;
    int c = (j < 40) ? j : j - 40;
    for (int i = t; i < 1024; i += 256)
      wsdT[(size_t)j * 1024 + i] = src[(size_t)i * 40 + c];
  }
}

// ---------- scores + topk (all fp32) ----------
__launch_bounds__(320)
__global__ void k_scores(const float* __restrict__ x, const float* __restrict__ wsdT,
                         int* __restrict__ eps_s, int* __restrict__ eps_d,
                         float* __restrict__ ss3, float* __restrict__ sd3) {
  int tokb = blockIdx.x * 8;
  __shared__ float xl[8][1028];
  __shared__ float sc[8][80];
  const float4* xsrc = reinterpret_cast<const float4*>(x + (size_t)tokb * 1024);
  for (int i = threadIdx.x; i < 2048; i += 320) {
    int tok = i >> 8, col4 = i & 255;
    *reinterpret_cast<float4*>(&xl[tok][col4 * 4]) = xsrc[i];
  }
  __syncthreads();
  {
    int tok = threadIdx.x & 7, j = threadIdx.x >> 3;
    const float4* wsp = reinterpret_cast<const float4*>(wsdT + (size_t)j * 1024);
    const float4* wdp = reinterpret_cast<const float4*>(wsdT + (size_t)(j + 40) * 1024);
    float as0 = 0.f, as1 = 0.f, ad0 = 0.f, ad1 = 0.f;
    #pragma unroll 4
    for (int k4 = 0; k4 < 256; k4 += 2) {
      float4 x0 = *reinterpret_cast<const float4*>(&xl[tok][k4 * 4]);
      float4 x1 = *reinterpret_cast<const float4*>(&xl[tok][k4 * 4 + 4]);
      float4 wsv0 = wsp[k4], wsv1 = wsp[k4 + 1];
      float4 wdv0 = wdp[k4], wdv1 = wdp[k4 + 1];
      as0 += x0.x * wsv0.x + x0.y * wsv0.y + x0.z * wsv0.z + x0.w * wsv0.w;
      as1 += x1.x * wsv1.x + x1.y * wsv1.y + x1.z * wsv1.z + x1.w * wsv1.w;
      ad0 += x0.x * wdv0.x + x0.y * wdv0.y + x0.z * wdv0.z + x0.w * wdv0.w;
      ad1 += x1.x * wdv1.x + x1.y * wdv1.y + x1.z * wdv1.z + x1.w * wdv1.w;
    }
    float as = as0 + as1, ad = ad0 + ad1;
    sc[tok][j]      = 1.f / (1.f + expf(-as));
    sc[tok][40 + j] = 1.f / (1.f + expf(-ad));
  }
  __syncthreads();
  int t2 = threadIdx.x;
  if (t2 < 128) {
    int tt = t2 >> 4, u = t2 & 15, h = u >> 1, which = u & 1;
    const float* S = &sc[tt][which * 40 + h * 5];
    float v[5];
    #pragma unroll
    for (int e = 0; e < 5; e++) v[e] = S[e];
    int tok = tokb + tt;
    int base = (tok * 8 + h) * 3;
    int* eps = which ? eps_d : eps_s;
    float* w3 = which ? sd3 : ss3;
    bool used[5] = {false, false, false, false, false};
    #pragma unroll
    for (int kk = 0; kk < 3; kk++) {
      float best = -1e30f; int bi = 0;
      #pragma unroll
      for (int e = 0; e < 5; e++)
        if (!used[e] && v[e] > best) { best = v[e]; bi = e; }
      used[bi] = true;
      eps[base + kk] = bi;
    }
    #pragma unroll
    for (int kk = 0; kk < 3; kk++) w3[base + kk] = S[kk]; // FIRST-K raw scores
  }
}

// ---------- fused projection + expert-select ----------
// grid (32, 8, 3)  block 512 (8 waves). M=128 tokens, N=320 (E*D), K=1024, BK=64.
// Verified optimum of 3 structures tried: 80.9us, 795 TF, MfmaUtil 33%.
__launch_bounds__(512)
__global__ void k_proj(const u16* __restrict__ xb, const u16* __restrict__ wT,
                       const int* __restrict__ eps_d, const int* __restrict__ eps_s,
                       const float* __restrict__ sd3, const float* __restrict__ ss3,
                       u16* __restrict__ qw, u16* __restrict__ kw, u16* __restrict__ vw) {
  int tok0 = blockIdx.x * 128;
  int h = blockIdx.y;
  int s = blockIdx.z;
  int Rbase = (s * 8 + h) * 320;
  __shared__ alignas(16) u16 bsA[128 * 64];
  __shared__ alignas(16) u16 bsB[320 * 64];
  int wv = threadIdx.x >> 6, l = threadIdx.x & 63;
  int g = l >> 4, c = l & 15;
  f32x4 acc[20];
  #pragma unroll
  for (int i = 0; i < 20; i++) acc[i] = (f32x4){0.f, 0.f, 0.f, 0.f};

  const u16* wTp0 = wT + (size_t)Rbase * 1024;
  const u16* xbp0 = xb + (size_t)tok0 * 1024;

  for (int k0 = 0; k0 < 1024; k0 += 64) {
    __syncthreads();
    const u16* wTp = wTp0 + k0;
    #pragma unroll
    for (int j = 0; j < 5; j++) {
      int ch = wv * 320 + j * 64 + l;
      int row = ch >> 3, part = ch & 7;
      gld16(wTp + (size_t)row * 1024 + ((part * 8) ^ ((row & 7) * 8)),
            &bsB[(wv * 320 + j * 64) * 8]);
    }
    const u16* xbp = xbp0 + k0;
    #pragma unroll
    for (int j = 0; j < 2; j++) {
      int ch = wv * 128 + j * 64 + l;
      int row = ch >> 3, part = ch & 7;
      gld16(xbp + (size_t)row * 1024 + ((part * 8) ^ ((row & 7) * 8)),
            &bsA[(wv * 128 + j * 64) * 8]);
    }
    __syncthreads();

    #pragma unroll
    for (int kk = 0; kk < 2; kk++) {
      int off = (kk * 32 + g * 8) ^ ((c & 7) * 8);
      s16x8 a = *reinterpret_cast<const s16x8*>(&bsA[(wv * 16 + c) * 64 + off]);
      #pragma unroll
      for (int nt = 0; nt < 20; nt++) {
        s16x8 b = *reinterpret_cast<const s16x8*>(&bsB[(nt * 16 + c) * 64 + off]);
        acc[nt] = mfma16(a, b, acc[nt]);
      }
    }
  }

  const int* eps = (s == 0) ? eps_d : eps_s;
  const float* w3 = (s == 0) ? sd3 : ss3;
  float scale = (s == 0) ? 0.125f : 1.0f;
  u16* dst = (s == 0) ? qw : (s == 1 ? kw : vw);
  #pragma unroll
  for (int r = 0; r < 4; r++) {
    int tokr = tok0 + wv * 16 + g * 4 + r;
    int base = (tokr * 8 + h) * 3;
    int e0 = eps[base], e1 = eps[base + 1], e2 = eps[base + 2];
    float w0 = w3[base], w1 = w3[base + 1], w2 = w3[base + 2];
    float we[5];
    #pragma unroll
    for (int e = 0; e < 5; e++)
      we[e] = (e0 == e ? w0 : 0.f) + (e1 == e ? w1 : 0.f) + (e2 == e ? w2 : 0.f);
    int b = tokr >> 11, t = tokr & 2047;
    size_t obase = (((size_t)b * 8 + h) * 2048 + t) * 64;
    #pragma unroll
    for (int dh = 0; dh < 4; dh++) {
      float vq = 0.f;
      #pragma unroll
      for (int e = 0; e < 5; e++) vq += we[e] * acc[e * 4 + dh][r];
      dst[obase + dh * 16 + c] = f2bf(vq * scale);
    }
  }
}

// (B,H,T,D) -> (B,H,D,T') with T' mu-permuted inside each 32-key tile:
// storage position p(k) = 8*((k&15)>>2) + (k&3) + (k>=16 ? 4 : 0).
__global__ void k_trv(const u16* __restrict__ vw, u16* __restrict__ vT) {
  int bh = blockIdx.z;
  int t0 = blockIdx.x * 32, d0 = blockIdx.y * 32;
  __shared__ u16 tile[32][33];
  const u16* src = vw + (size_t)bh * 2048 * 64;
  u16* dst = vT + (size_t)bh * 64 * 2048;
  int tx = threadIdx.x, ty = threadIdx.y;
  #pragma unroll
  for (int i = 0; i < 4; i++)
    tile[ty + 8 * i][tx] = src[(size_t)(t0 + ty + 8 * i) * 64 + d0 + tx];
  __syncthreads();
  int p = 8 * ((tx & 15) >> 2) + (tx & 3) + ((tx >= 16) ? 4 : 0);
  #pragma unroll
  for (int i = 0; i < 4; i++)
    dst[(size_t)(d0 + ty + 8 * i) * 2048 + t0 + p] = tile[tx][ty + 8 * i];
}

// ---------- flash attention: 8 waves, split-KV x2, LDS-staged K/V ----------
__launch_bounds__(512)
__global__ void k_attn(const u16* __restrict__ qw, const u16* __restrict__ kw,
                       const u16* __restrict__ vT, u16* __restrict__ ow) {
  int bh = blockIdx.y;
  int b = bh >> 3, h = bh & 7;
  int q0 = blockIdx.x * 64;
  int wv = threadIdx.x >> 6, l = threadIdx.x & 63;
  int seg = wv >> 2, wq = wv & 3;
  int g = l >> 4, c = l & 15;
  const u16* qp = qw + (size_t)bh * 2048 * 64;
  const u16* kp = kw + (size_t)bh * 2048 * 64;
  const u16* vp = vT + (size_t)bh * 64 * 2048;
  __shared__ alignas(16) u16 Kl[2][128 * 64];   // 32 KB
  __shared__ alignas(16) u16 Vl[2][64 * 128];   // 32 KB

  s16x8 qa0 = ld8(qp + (size_t)(q0 + wq * 16 + c) * 64 + 0 + 8 * g);
  s16x8 qa1 = ld8(qp + (size_t)(q0 + wq * 16 + c) * 64 + 32 + 8 * g);

  f32x4 o[4];
  #pragma unroll
  for (int i = 0; i < 4; i++) o[i] = (f32x4){0.f, 0.f, 0.f, 0.f};
  float ssum = 0.f;

  const int kb0 = seg * 1024;
  for (int kt = 0; kt < 1024; kt += 128) {
    int kbase = kb0 + kt;
    __syncthreads();
    #pragma unroll
    for (int j = 0; j < 4; j++) {
      int ch = (wq * 4 + j) * 64 + l;
      int row = ch >> 3, sl = ch & 7;
      gld16(kp + (size_t)(kbase + row) * 64 + ((sl ^ (row & 7)) * 8),
            &Kl[seg][(wq * 4 + j) * 64 * 8]);
    }
    #pragma unroll
    for (int j = 0; j < 4; j++) {
      int ch = (wq * 4 + j) * 64 + l;
      int d = ch >> 4, sl = ch & 15;
      gld16(vp + (size_t)d * 2048 + kbase + ((sl ^ (d & 15)) * 8),
            &Vl[seg][(wq * 4 + j) * 64 * 8]);
    }
    __syncthreads();

    #pragma unroll
    for (int kk = 0; kk < 4; kk++) {
      int r0 = kk * 32 + c, r1 = kk * 32 + 16 + c;
      int c7 = c & 7;
      s16x8 ka0 = *reinterpret_cast<const s16x8*>(&Kl[seg][r0 * 64 + ((0 + g) ^ c7) * 8]);
      s16x8 ka1 = *reinterpret_cast<const s16x8*>(&Kl[seg][r0 * 64 + ((4 + g) ^ c7) * 8]);
      s16x8 kc0 = *reinterpret_cast<const s16x8*>(&Kl[seg][r1 * 64 + ((0 + g) ^ c7) * 8]);
      s16x8 kc1 = *reinterpret_cast<const s16x8*>(&Kl[seg][r1 * 64 + ((4 + g) ^ c7) * 8]);

      f32x4 s0 = (f32x4){0.f, 0.f, 0.f, 0.f};
      f32x4 s1 = (f32x4){0.f, 0.f, 0.f, 0.f};
      s0 = mfma16(ka0, qa0, s0);
      s0 = mfma16(ka1, qa1, s0);
      s1 = mfma16(kc0, qa0, s1);
      s1 = mfma16(kc1, qa1, s1);

      float p00 = __expf(s0[0]), p01 = __expf(s0[1]);
      float p02 = __expf(s0[2]), p03 = __expf(s0[3]);
      float p10 = __expf(s1[0]), p11 = __expf(s1[1]);
      float p12 = __expf(s1[2]), p13 = __expf(s1[3]);
      ssum += (p00 + p01) + (p02 + p03) + (p10 + p11) + (p12 + p13);

      uint4 pw = make_uint4(pk2(p00, p01), pk2(p02, p03),
                            pk2(p10, p11), pk2(p12, p13));
      s16x8 pa = __builtin_bit_cast(s16x8, pw);

      #pragma unroll
      for (int nt = 0; nt < 4; nt++) {
        int d = nt * 16 + c;
        s16x8 vb = *reinterpret_cast<const s16x8*>(&Vl[seg][d * 128 + (((kk * 4 + g) ^ (d & 15)) * 8)]);
        o[nt] = mfma16(pa, vb, o[nt]);
      }
    }
  }

  // per-lane ssum covers this seg's keys for q=c; reduce over g (bits 4,5).
  ssum += __shfl_xor(ssum, 16, 64);
  ssum += __shfl_xor(ssum, 32, 64);

  // combine epilogue: alias os/ssl onto Kl/Vl after all LDS reads complete.
  float* osp  = reinterpret_cast<float*>(&Kl[0][0]);   // [4][16][64] = 16 KB
  float* sslp = reinterpret_cast<float*>(&Vl[0][0]);   // [2][4][16]
  __syncthreads();
  if (g == 0) sslp[seg * 64 + wq * 16 + c] = ssum;
  if (seg == 1) {
    #pragma unroll
    for (int r = 0; r < 4; r++)
      #pragma unroll
      for (int nt = 0; nt < 4; nt++)
        osp[(wq * 16 + g * 4 + r) * 64 + nt * 16 + c] = o[nt][r];
  }
  __syncthreads();
  if (seg == 0) {
    #pragma unroll
    for (int r = 0; r < 4; r++) {
      int q = g * 4 + r;
      float sm = sslp[wq * 16 + q] + sslp[64 + wq * 16 + q];
      float inv = 1.f / sm;
      int t = q0 + wq * 16 + q;
      #pragma unroll
      for (int nt = 0; nt < 4; nt++) {
        float val = (o[nt][r] + osp[(wq * 16 + q) * 64 + nt * 16 + c]) * inv;
        ow[((size_t)(b * 2048 + t)) * 512 + h * 64 + nt * 16 + c] = f2bf(val);
      }
    }
  }
}

// ---------- output projection ----------
__launch_bounds__(512)
__global__ void k_oproj(const u16* __restrict__ ow, const u16* __restrict__ woT,
                        const float* __restrict__ biasum, float* __restrict__ out) {
  int t0 = blockIdx.x * 128, f0 = blockIdx.y * 64;
  int wv = threadIdx.x >> 6, l = threadIdx.x & 63;
  int g = l >> 4, c = l & 15;
  f32x4 acc[4];
  #pragma unroll
  for (int i = 0; i < 4; i++) acc[i] = (f32x4){0.f, 0.f, 0.f, 0.f};
  for (int k0 = 0; k0 < 512; k0 += 32) {
    s16x8 a = ld8(ow + (size_t)(t0 + wv * 16 + c) * 512 + k0 + 8 * g);
    #pragma unroll
    for (int nt = 0; nt < 4; nt++) {
      s16x8 bfr = ld8(woT + (size_t)(f0 + nt * 16 + c) * 512 + k0 + 8 * g);
      acc[nt] = mfma16(a, bfr, acc[nt]);
    }
  }
  #pragma unroll
  for (int r = 0; r < 4; r++) {
    int t = t0 + wv * 16 + g * 4 + r;
    #pragma unroll
    for (int nt = 0; nt < 4; nt++) {
      int f = f0 + nt * 16 + c;
      out[(size_t)t * 1024 + f] = acc[nt][r] + biasum[f];
    }
  }
}

extern "C" void kernel_launch(void* const* d_in, const int* in_sizes, int n_in,
                              void* d_out, int out_size, void* d_ws, size_t ws_size,
                              hipStream_t stream) {
  const float* x    = (const float*)d_in[0];
  const float* w_q  = (const float*)d_in[1];
  const float* w_kv = (const float*)d_in[2];
  const float* w_s  = (const float*)d_in[3];
  const float* w_d  = (const float*)d_in[4];
  const float* w_ow = (const float*)d_in[5];
  const float* w_ob = (const float*)d_in[6];
  float* out = (float*)d_out;

  char* ws = (char*)d_ws;
  size_t o = 0;
  u16* xb     = (u16*)(ws + o); o += (size_t)NTOK * DIMc * 2;
  u16* wT     = (u16*)(ws + o); o += (size_t)3 * NQ * DIMc * 2;
  u16* woT    = (u16*)(ws + o); o += (size_t)1024 * 512 * 2;
  float* bsum = (float*)(ws + o); o += 4096;
  float* wsdT = (float*)(ws + o); o += (size_t)80 * 1024 * 4;
  int* eps_s  = (int*)(ws + o); o += (size_t)NTOK * 8 * 3 * 4;
  int* eps_d  = (int*)(ws + o); o += (size_t)NTOK * 8 * 3 * 4;
  float* ss3  = (float*)(ws + o); o += (size_t)NTOK * 8 * 3 * 4;
  float* sd3  = (float*)(ws + o); o += (size_t)NTOK * 8 * 3 * 4;
  u16* qw     = (u16*)(ws + o); o += (size_t)NTOK * 512 * 2;
  u16* kw     = (u16*)(ws + o); o += (size_t)NTOK * 512 * 2;
  u16* vw     = (u16*)(ws + o); o += (size_t)NTOK * 512 * 2;
  u16* vTw    = (u16*)(ws + o); o += (size_t)NTOK * 512 * 2;
  u16* oww    = (u16*)(ws + o); o += (size_t)NTOK * 512 * 2;

  k_prep<<<12116, 256, 0, stream>>>(x, w_q, w_kv, w_ow, w_ob, w_s, w_d,
                                    xb, wT, woT, bsum, wsdT);
  k_scores<<<512, 320, 0, stream>>>(x, wsdT, eps_s, eps_d, ss3, sd3);
  k_proj<<<dim3(32, 8, 3), 512, 0, stream>>>(xb, wT, eps_d, eps_s, sd3, ss3, qw, kw, vw);
  k_trv<<<dim3(64, 2, 16), dim3(32, 8), 0, stream>>>(vw, vTw);
  k_attn<<<dim3(32, 16), 512, 0, stream>>>(qw, kw, vTw, oww);
  k_oproj<<<dim3(32, 16), 512, 0, stream>>>(oww, woT, bsum, out);
}

// Round 15
// 206.971 us; speedup vs baseline: 1.0354x; 1.0182x over previous
//
#include <hip/hip_runtime.h>

#define DEV __device__ __forceinline__

typedef float f32x4 __attribute__((ext_vector_type(4)));
typedef short s16x8 __attribute__((ext_vector_type(8)));
typedef unsigned short u16;
typedef unsigned int u32;

constexpr int Bb = 2, Tt = 2048, DIMc = 1024, Hh = 8, Ee = 5, Dd = 64;
constexpr int NTOK = Bb * Tt;   // 4096
constexpr int NQ = Hh * Ee * Dd; // 2560

DEV u16 f2bf(float f) {
  union { float f; u32 u; } v; v.f = f;
  u32 r = v.u + 0x7fffu + ((v.u >> 16) & 1u);
  return (u16)(r >> 16);
}

DEV u32 pk2(float a, float b) {  // two f32 -> packed bf16 pair (a=lo, b=hi)
  return (u32)f2bf(a) | ((u32)f2bf(b) << 16);
}

// single-instruction packed conversion (HW: v_cvt_pk_bf16_f32, m214v22)
DEV u32 pk2a(float a, float b) {
  u32 r;
  asm("v_cvt_pk_bf16_f32 %0, %1, %2" : "=v"(r) : "v"(a), "v"(b));
  return r;
}

DEV s16x8 ld8(const u16* p) {
  uint4 u = *reinterpret_cast<const uint4*>(p);
  return __builtin_bit_cast(s16x8, u);
}

DEV f32x4 mfma16(s16x8 a, s16x8 b, f32x4 c) {
  return __builtin_amdgcn_mfma_f32_16x16x32_bf16(a, b, c, 0, 0, 0);
}

// async global->LDS, 16B per lane. LDS dest = uniform base + lane*16.
DEV void gld16(const void* g, void* l) {
  __builtin_amdgcn_global_load_lds(
      (const __attribute__((address_space(1))) void*)g,
      (__attribute__((address_space(3))) void*)l, 16, 0, 0);
}

// ---------- fused prep kernel ----------
// blocks [0,4096): cvt x->bf16 ; [4096,11776): transpose w_q/w_kv -> wT ;
// [11776,12032): w_o_w -> woT ; [12032,12036): bias sum ; [12036,12116): wsdT.
__launch_bounds__(256)
__global__ void k_prep(const float* __restrict__ x, const float* __restrict__ wq,
                       const float* __restrict__ wkv, const float* __restrict__ wow,
                       const float* __restrict__ wob, const float* __restrict__ wsr,
                       const float* __restrict__ wdr,
                       u16* __restrict__ xb, u16* __restrict__ wT,
                       u16* __restrict__ woT, float* __restrict__ bsum,
                       float* __restrict__ wsdT) {
  int bid = blockIdx.x, t = threadIdx.x;
  if (bid < 4096) {
    int i = bid * 256 + t;
    float4 v = reinterpret_cast<const float4*>(x)[i];
    u16 r0 = f2bf(v.x), r1 = f2bf(v.y), r2 = f2bf(v.z), r3 = f2bf(v.w);
    u32 lo = (u32)r0 | ((u32)r1 << 16);
    u32 hi = (u32)r2 | ((u32)r3 << 16);
    reinterpret_cast<uint2*>(xb)[i] = make_uint2(lo, hi);
  } else if (bid < 11776) {
    int b2 = bid - 4096;
    int R0 = (b2 % 240) * 32;
    int C0 = (b2 / 240) * 32;
    int s = R0 / 2560, rem = R0 % 2560;
    int h = rem / 320, n0 = rem % 320;
    const float* src; int ld; int col0;
    if (s == 0) { src = wq;  ld = 2560; col0 = h * 320 + n0; }
    else        { src = wkv; ld = 5120; col0 = (s - 1) * 2560 + h * 320 + n0; }
    __shared__ float tile[32][33];
    int tx = t & 31, ty = t >> 5;
    #pragma unroll
    for (int i = 0; i < 4; i++) {
      int c = C0 + ty + 8 * i;
      tile[ty + 8 * i][tx] = src[(size_t)c * ld + col0 + tx];
    }
    __syncthreads();
    #pragma unroll
    for (int i = 0; i < 4; i++) {
      int n = ty + 8 * i;
      wT[(size_t)(R0 + n) * 1024 + C0 + tx] = f2bf(tile[tx][n]);
    }
  } else if (bid < 12032) {
    int b2 = bid - 11776;
    int f = b2 * 4 + (t >> 6), d = t & 63;
    #pragma unroll
    for (int h = 0; h < 8; h++)
      woT[(size_t)f * 512 + h * 64 + d] = f2bf(wow[((size_t)h * 1024 + f) * 64 + d]);
  } else if (bid < 12036) {
    int f = (bid - 12032) * 256 + t;
    float s = 0.f;
    #pragma unroll
    for (int h = 0; h < 8; h++) s += wob[h * 1024 + f];
    bsum[f] = s;
  } else {
    int j = bid - 12036;
    const float* src = (j < 40) ? wsr : wdr;
    int c = (j < 40) ? j : j - 40;
    for (int i = t; i < 1024; i += 256)
      wsdT[(size_t)j * 1024 + i] = src[(size_t)i * 40 + c];
  }
}

// ---------- scores + topk (all fp32) ----------
__launch_bounds__(320)
__global__ void k_scores(const float* __restrict__ x, const float* __restrict__ wsdT,
                         int* __restrict__ eps_s, int* __restrict__ eps_d,
                         float* __restrict__ ss3, float* __restrict__ sd3) {
  int tokb = blockIdx.x * 8;
  __shared__ float xl[8][1028];
  __shared__ float sc[8][80];
  const float4* xsrc = reinterpret_cast<const float4*>(x + (size_t)tokb * 1024);
  for (int i = threadIdx.x; i < 2048; i += 320) {
    int tok = i >> 8, col4 = i & 255;
    *reinterpret_cast<float4*>(&xl[tok][col4 * 4]) = xsrc[i];
  }
  __syncthreads();
  {
    int tok = threadIdx.x & 7, j = threadIdx.x >> 3;
    const float4* wsp = reinterpret_cast<const float4*>(wsdT + (size_t)j * 1024);
    const float4* wdp = reinterpret_cast<const float4*>(wsdT + (size_t)(j + 40) * 1024);
    float as0 = 0.f, as1 = 0.f, ad0 = 0.f, ad1 = 0.f;
    #pragma unroll 4
    for (int k4 = 0; k4 < 256; k4 += 2) {
      float4 x0 = *reinterpret_cast<const float4*>(&xl[tok][k4 * 4]);
      float4 x1 = *reinterpret_cast<const float4*>(&xl[tok][k4 * 4 + 4]);
      float4 wsv0 = wsp[k4], wsv1 = wsp[k4 + 1];
      float4 wdv0 = wdp[k4], wdv1 = wdp[k4 + 1];
      as0 += x0.x * wsv0.x + x0.y * wsv0.y + x0.z * wsv0.z + x0.w * wsv0.w;
      as1 += x1.x * wsv1.x + x1.y * wsv1.y + x1.z * wsv1.z + x1.w * wsv1.w;
      ad0 += x0.x * wdv0.x + x0.y * wdv0.y + x0.z * wdv0.z + x0.w * wdv0.w;
      ad1 += x1.x * wdv1.x + x1.y * wdv1.y + x1.z * wdv1.z + x1.w * wdv1.w;
    }
    float as = as0 + as1, ad = ad0 + ad1;
    sc[tok][j]      = 1.f / (1.f + expf(-as));
    sc[tok][40 + j] = 1.f / (1.f + expf(-ad));
  }
  __syncthreads();
  int t2 = threadIdx.x;
  if (t2 < 128) {
    int tt = t2 >> 4, u = t2 & 15, h = u >> 1, which = u & 1;
    const float* S = &sc[tt][which * 40 + h * 5];
    float v[5];
    #pragma unroll
    for (int e = 0; e < 5; e++) v[e] = S[e];
    int tok = tokb + tt;
    int base = (tok * 8 + h) * 3;
    int* eps = which ? eps_d : eps_s;
    float* w3 = which ? sd3 : ss3;
    bool used[5] = {false, false, false, false, false};
    #pragma unroll
    for (int kk = 0; kk < 3; kk++) {
      float best = -1e30f; int bi = 0;
      #pragma unroll
      for (int e = 0; e < 5; e++)
        if (!used[e] && v[e] > best) { best = v[e]; bi = e; }
      used[bi] = true;
      eps[base + kk] = bi;
    }
    #pragma unroll
    for (int kk = 0; kk < 3; kk++) w3[base + kk] = S[kk]; // FIRST-K raw scores
  }
}

// ---------- fused projection + expert-select ----------
// grid (32, 8, 3)  block 512 (8 waves). M=128 tokens, N=320 (E*D), K=1024, BK=64.
// Verified optimum of 3 structures tried: 80.9us, 795 TF, MfmaUtil 33%.
__launch_bounds__(512)
__global__ void k_proj(const u16* __restrict__ xb, const u16* __restrict__ wT,
                       const int* __restrict__ eps_d, const int* __restrict__ eps_s,
                       const float* __restrict__ sd3, const float* __restrict__ ss3,
                       u16* __restrict__ qw, u16* __restrict__ kw, u16* __restrict__ vw) {
  int tok0 = blockIdx.x * 128;
  int h = blockIdx.y;
  int s = blockIdx.z;
  int Rbase = (s * 8 + h) * 320;
  __shared__ alignas(16) u16 bsA[128 * 64];
  __shared__ alignas(16) u16 bsB[320 * 64];
  int wv = threadIdx.x >> 6, l = threadIdx.x & 63;
  int g = l >> 4, c = l & 15;
  f32x4 acc[20];
  #pragma unroll
  for (int i = 0; i < 20; i++) acc[i] = (f32x4){0.f, 0.f, 0.f, 0.f};

  const u16* wTp0 = wT + (size_t)Rbase * 1024;
  const u16* xbp0 = xb + (size_t)tok0 * 1024;

  for (int k0 = 0; k0 < 1024; k0 += 64) {
    __syncthreads();
    const u16* wTp = wTp0 + k0;
    #pragma unroll
    for (int j = 0; j < 5; j++) {
      int ch = wv * 320 + j * 64 + l;
      int row = ch >> 3, part = ch & 7;
      gld16(wTp + (size_t)row * 1024 + ((part * 8) ^ ((row & 7) * 8)),
            &bsB[(wv * 320 + j * 64) * 8]);
    }
    const u16* xbp = xbp0 + k0;
    #pragma unroll
    for (int j = 0; j < 2; j++) {
      int ch = wv * 128 + j * 64 + l;
      int row = ch >> 3, part = ch & 7;
      gld16(xbp + (size_t)row * 1024 + ((part * 8) ^ ((row & 7) * 8)),
            &bsA[(wv * 128 + j * 64) * 8]);
    }
    __syncthreads();

    #pragma unroll
    for (int kk = 0; kk < 2; kk++) {
      int off = (kk * 32 + g * 8) ^ ((c & 7) * 8);
      s16x8 a = *reinterpret_cast<const s16x8*>(&bsA[(wv * 16 + c) * 64 + off]);
      #pragma unroll
      for (int nt = 0; nt < 20; nt++) {
        s16x8 b = *reinterpret_cast<const s16x8*>(&bsB[(nt * 16 + c) * 64 + off]);
        acc[nt] = mfma16(a, b, acc[nt]);
      }
    }
  }

  const int* eps = (s == 0) ? eps_d : eps_s;
  const float* w3 = (s == 0) ? sd3 : ss3;
  float scale = (s == 0) ? 0.125f : 1.0f;
  u16* dst = (s == 0) ? qw : (s == 1 ? kw : vw);
  #pragma unroll
  for (int r = 0; r < 4; r++) {
    int tokr = tok0 + wv * 16 + g * 4 + r;
    int base = (tokr * 8 + h) * 3;
    int e0 = eps[base], e1 = eps[base + 1], e2 = eps[base + 2];
    float w0 = w3[base], w1 = w3[base + 1], w2 = w3[base + 2];
    float we[5];
    #pragma unroll
    for (int e = 0; e < 5; e++)
      we[e] = (e0 == e ? w0 : 0.f) + (e1 == e ? w1 : 0.f) + (e2 == e ? w2 : 0.f);
    int b = tokr >> 11, t = tokr & 2047;
    size_t obase = (((size_t)b * 8 + h) * 2048 + t) * 64;
    #pragma unroll
    for (int dh = 0; dh < 4; dh++) {
      float vq = 0.f;
      #pragma unroll
      for (int e = 0; e < 5; e++) vq += we[e] * acc[e * 4 + dh][r];
      dst[obase + dh * 16 + c] = f2bf(vq * scale);
    }
  }
}

// (B,H,T,D) -> (B,H,D,T') with T' mu-permuted inside each 32-key tile:
// storage position p(k) = 8*((k&15)>>2) + (k&3) + (k>=16 ? 4 : 0).
__global__ void k_trv(const u16* __restrict__ vw, u16* __restrict__ vT) {
  int bh = blockIdx.z;
  int t0 = blockIdx.x * 32, d0 = blockIdx.y * 32;
  __shared__ u16 tile[32][33];
  const u16* src = vw + (size_t)bh * 2048 * 64;
  u16* dst = vT + (size_t)bh * 64 * 2048;
  int tx = threadIdx.x, ty = threadIdx.y;
  #pragma unroll
  for (int i = 0; i < 4; i++)
    tile[ty + 8 * i][tx] = src[(size_t)(t0 + ty + 8 * i) * 64 + d0 + tx];
  __syncthreads();
  int p = 8 * ((tx & 15) >> 2) + (tx & 3) + ((tx >= 16) ? 4 : 0);
  #pragma unroll
  for (int i = 0; i < 4; i++)
    dst[(size_t)(d0 + ty + 8 * i) * 2048 + t0 + p] = tile[tx][ty + 8 * i];
}

// ---------- flash attention: 8 waves, split-KV x2, LDS-staged K/V ----------
__launch_bounds__(512)
__global__ void k_attn(const u16* __restrict__ qw, const u16* __restrict__ kw,
                       const u16* __restrict__ vT, u16* __restrict__ ow) {
  int bh = blockIdx.y;
  int b = bh >> 3, h = bh & 7;
  int q0 = blockIdx.x * 64;
  int wv = threadIdx.x >> 6, l = threadIdx.x & 63;
  int seg = wv >> 2, wq = wv & 3;
  int g = l >> 4, c = l & 15;
  const u16* qp = qw + (size_t)bh * 2048 * 64;
  const u16* kp = kw + (size_t)bh * 2048 * 64;
  const u16* vp = vT + (size_t)bh * 64 * 2048;
  __shared__ alignas(16) u16 Kl[2][128 * 64];   // 32 KB
  __shared__ alignas(16) u16 Vl[2][64 * 128];   // 32 KB

  s16x8 qa0 = ld8(qp + (size_t)(q0 + wq * 16 + c) * 64 + 0 + 8 * g);
  s16x8 qa1 = ld8(qp + (size_t)(q0 + wq * 16 + c) * 64 + 32 + 8 * g);

  f32x4 o[4];
  #pragma unroll
  for (int i = 0; i < 4; i++) o[i] = (f32x4){0.f, 0.f, 0.f, 0.f};
  float ssum = 0.f;

  const int kb0 = seg * 1024;
  for (int kt = 0; kt < 1024; kt += 128) {
    int kbase = kb0 + kt;
    __syncthreads();
    #pragma unroll
    for (int j = 0; j < 4; j++) {
      int ch = (wq * 4 + j) * 64 + l;
      int row = ch >> 3, sl = ch & 7;
      gld16(kp + (size_t)(kbase + row) * 64 + ((sl ^ (row & 7)) * 8),
            &Kl[seg][(wq * 4 + j) * 64 * 8]);
    }
    #pragma unroll
    for (int j = 0; j < 4; j++) {
      int ch = (wq * 4 + j) * 64 + l;
      int d = ch >> 4, sl = ch & 15;
      gld16(vp + (size_t)d * 2048 + kbase + ((sl ^ (d & 15)) * 8),
            &Vl[seg][(wq * 4 + j) * 64 * 8]);
    }
    __syncthreads();

    #pragma unroll
    for (int kk = 0; kk < 4; kk++) {
      int r0 = kk * 32 + c, r1 = kk * 32 + 16 + c;
      int c7 = c & 7;
      s16x8 ka0 = *reinterpret_cast<const s16x8*>(&Kl[seg][r0 * 64 + ((0 + g) ^ c7) * 8]);
      s16x8 ka1 = *reinterpret_cast<const s16x8*>(&Kl[seg][r0 * 64 + ((4 + g) ^ c7) * 8]);
      s16x8 kc0 = *reinterpret_cast<const s16x8*>(&Kl[seg][r1 * 64 + ((0 + g) ^ c7) * 8]);
      s16x8 kc1 = *reinterpret_cast<const s16x8*>(&Kl[seg][r1 * 64 + ((4 + g) ^ c7) * 8]);

      f32x4 s0 = (f32x4){0.f, 0.f, 0.f, 0.f};
      f32x4 s1 = (f32x4){0.f, 0.f, 0.f, 0.f};
      s0 = mfma16(ka0, qa0, s0);
      s0 = mfma16(ka1, qa1, s0);
      s1 = mfma16(kc0, qa0, s1);
      s1 = mfma16(kc1, qa1, s1);

      float p00 = __expf(s0[0]), p01 = __expf(s0[1]);
      float p02 = __expf(s0[2]), p03 = __expf(s0[3]);
      float p10 = __expf(s1[0]), p11 = __expf(s1[1]);
      float p12 = __expf(s1[2]), p13 = __expf(s1[3]);
      ssum += (p00 + p01) + (p02 + p03) + (p10 + p11) + (p12 + p13);

      // single-instruction packed bf16 conversion (replaces 3-op f2bf pairs)
      uint4 pw = make_uint4(pk2a(p00, p01), pk2a(p02, p03),
                            pk2a(p10, p11), pk2a(p12, p13));
      s16x8 pa = __builtin_bit_cast(s16x8, pw);

      #pragma unroll
      for (int nt = 0; nt < 4; nt++) {
        int d = nt * 16 + c;
        s16x8 vb = *reinterpret_cast<const s16x8*>(&Vl[seg][d * 128 + (((kk * 4 + g) ^ (d & 15)) * 8)]);
        o[nt] = mfma16(pa, vb, o[nt]);
      }
    }
  }

  // per-lane ssum covers this seg's keys for q=c; reduce over g (bits 4,5).
  ssum += __shfl_xor(ssum, 16, 64);
  ssum += __shfl_xor(ssum, 32, 64);

  // combine epilogue: alias os/ssl onto Kl/Vl after all LDS reads complete.
  float* osp  = reinterpret_cast<float*>(&Kl[0][0]);   // [4][16][64] = 16 KB
  float* sslp = reinterpret_cast<float*>(&Vl[0][0]);   // [2][4][16]
  __syncthreads();
  if (g == 0) sslp[seg * 64 + wq * 16 + c] = ssum;
  if (seg == 1) {
    #pragma unroll
    for (int r = 0; r < 4; r++)
      #pragma unroll
      for (int nt = 0; nt < 4; nt++)
        osp[(wq * 16 + g * 4 + r) * 64 + nt * 16 + c] = o[nt][r];
  }
  __syncthreads();
  if (seg == 0) {
    #pragma unroll
    for (int r = 0; r < 4; r++) {
      int q = g * 4 + r;
      float sm = sslp[wq * 16 + q] + sslp[64 + wq * 16 + q];
      float inv = 1.f / sm;
      int t = q0 + wq * 16 + q;
      #pragma unroll
      for (int nt = 0; nt < 4; nt++) {
        float val = (o[nt][r] + osp[(wq * 16 + q) * 64 + nt * 16 + c]) * inv;
        ow[((size_t)(b * 2048 + t)) * 512 + h * 64 + nt * 16 + c] = f2bf(val);
      }
    }
  }
}

// ---------- output projection ----------
__launch_bounds__(512)
__global__ void k_oproj(const u16* __restrict__ ow, const u16* __restrict__ woT,
                        const float* __restrict__ biasum, float* __restrict__ out) {
  int t0 = blockIdx.x * 128, f0 = blockIdx.y * 64;
  int wv = threadIdx.x >> 6, l = threadIdx.x & 63;
  int g = l >> 4, c = l & 15;
  f32x4 acc[4];
  #pragma unroll
  for (int i = 0; i < 4; i++) acc[i] = (f32x4){0.f, 0.f, 0.f, 0.f};
  for (int k0 = 0; k0 < 512; k0 += 32) {
    s16x8 a = ld8(ow + (size_t)(t0 + wv * 16 + c) * 512 + k0 + 8 * g);
    #pragma unroll
    for (int nt = 0; nt < 4; nt++) {
      s16x8 bfr = ld8(woT + (size_t)(f0 + nt * 16 + c) * 512 + k0 + 8 * g);
      acc[nt] = mfma16(a, bfr, acc[nt]);
    }
  }
  #pragma unroll
  for (int r = 0; r < 4; r++) {
    int t = t0 + wv * 16 + g * 4 + r;
    #pragma unroll
    for (int nt = 0; nt < 4; nt++) {
      int f = f0 + nt * 16 + c;
      out[(size_t)t * 1024 + f] = acc[nt][r] + biasum[f];
    }
  }
}

extern "C" void kernel_launch(void* const* d_in, const int* in_sizes, int n_in,
                              void* d_out, int out_size, void* d_ws, size_t ws_size,
                              hipStream_t stream) {
  const float* x    = (const float*)d_in[0];
  const float* w_q  = (const float*)d_in[1];
  const float* w_kv = (const float*)d_in[2];
  const float* w_s  = (const float*)d_in[3];
  const float* w_d  = (const float*)d_in[4];
  const float* w_ow = (const float*)d_in[5];
  const float* w_ob = (const float*)d_in[6];
  float* out = (float*)d_out;

  char* ws = (char*)d_ws;
  size_t o = 0;
  u16* xb     = (u16*)(ws + o); o += (size_t)NTOK * DIMc * 2;
  u16* wT     = (u16*)(ws + o); o += (size_t)3 * NQ * DIMc * 2;
  u16* woT    = (u16*)(ws + o); o += (size_t)1024 * 512 * 2;
  float* bsum = (float*)(ws + o); o += 4096;
  float* wsdT = (float*)(ws + o); o += (size_t)80 * 1024 * 4;
  int* eps_s  = (int*)(ws + o); o += (size_t)NTOK * 8 * 3 * 4;
  int* eps_d  = (int*)(ws + o); o += (size_t)NTOK * 8 * 3 * 4;
  float* ss3  = (float*)(ws + o); o += (size_t)NTOK * 8 * 3 * 4;
  float* sd3  = (float*)(ws + o); o += (size_t)NTOK * 8 * 3 * 4;
  u16* qw     = (u16*)(ws + o); o += (size_t)NTOK * 512 * 2;
  u16* kw     = (u16*)(ws + o); o += (size_t)NTOK * 512 * 2;
  u16* vw     = (u16*)(ws + o); o += (size_t)NTOK * 512 * 2;
  u16* vTw    = (u16*)(ws + o); o += (size_t)NTOK * 512 * 2;
  u16* oww    = (u16*)(ws + o); o += (size_t)NTOK * 512 * 2;

  k_prep<<<12116, 256, 0, stream>>>(x, w_q, w_kv, w_ow, w_ob, w_s, w_d,
                                    xb, wT, woT, bsum, wsdT);
  k_scores<<<512, 320, 0, stream>>>(x, wsdT, eps_s, eps_d, ss3, sd3);
  k_proj<<<dim3(32, 8, 3), 512, 0, stream>>>(xb, wT, eps_d, eps_s, sd3, ss3, qw, kw, vw);
  k_trv<<<dim3(64, 2, 16), dim3(32, 8), 0, stream>>>(vw, vTw);
  k_attn<<<dim3(32, 16), 512, 0, stream>>>(qw, kw, vTw, oww);
  k_oproj<<<dim3(32, 16), 512, 0, stream>>>(oww, woT, bsum, out);
}